// Round 7
// baseline (72.720 us; speedup 1.0000x reference)
//
#include <hip/hip_runtime.h>

#define BB 2
#define CC 64
#define CI 32
#define NPIX 9216            // 96*96
#define CH 64                // pixels per chunk/block
#define NCHK (NPIX / CH)     // 144 chunks per batch
#define NB (BB * NCHK)       // 288 blocks

// ---------------------------------------------------------------------------
// k1: M[batch] += (pw Xc + pb 1^T)(gw Xc + gb 1^T)^T   via fp32 HW atomics.
// Bias columns fold exactly into the per-chunk product (verified algebra):
// M = sum_c P' G'^T with P' = pw Xc + pb, G' = gw Xc + gb.
// ---------------------------------------------------------------------------
__global__ __launch_bounds__(256) void k1_M(
    const float* __restrict__ x, const float* __restrict__ pw,
    const float* __restrict__ pb, const float* __restrict__ gw,
    const float* __restrict__ gb, float* __restrict__ Mg) {
  __shared__ float xt[CC][CH + 4];   // [ch][px]  17.4 KB
  __shared__ float pws[CI][CC + 1];  // 8.3 KB
  __shared__ float gws[CI][CC + 1];  // 8.3 KB
  __shared__ float Ps[CI][CH + 2];   // 8.4 KB
  __shared__ float Gs[CI][CH + 2];   // 8.4 KB
  const int t = threadIdx.x;
  const int blk = blockIdx.x;
  const int batch = blk / NCHK;
  const int chk = blk - batch * NCHK;
  const float* __restrict__ X = x + (size_t)batch * CC * NPIX + chk * CH;

  // stage X chunk (64ch x 64px), coalesced float4
#pragma unroll
  for (int h = 0; h < 4; ++h) {
    const int idx = t + 256 * h;
    const int c = idx >> 4;
    const int p4 = (idx & 15) * 4;
    const float4 v =
        *reinterpret_cast<const float4*>(&X[(size_t)c * NPIX + p4]);
    *reinterpret_cast<float4*>(&xt[c][p4]) = v;
  }
  // stage pw, gw (32x64 each)
  for (int idx = t; idx < CI * CC; idx += 256) {
    const int k = idx >> 6, c = idx & 63;
    pws[k][c] = pw[idx];
    gws[k][c] = gw[idx];
  }
  __syncthreads();

  // P' = pw Xc + pb, G' = gw Xc + gb  (each thread: one k-row, 8 pixels)
  {
    const int k = t & 31;
    const int p0 = (t >> 5) * 8;
    float pa[8] = {};
    float ga[8] = {};
    for (int c = 0; c < CC; ++c) {
      const float pwv = pws[k][c];
      const float gwv = gws[k][c];
#pragma unroll
      for (int i = 0; i < 8; ++i) {
        const float xv = xt[c][p0 + i];
        pa[i] += pwv * xv;
        ga[i] += gwv * xv;
      }
    }
    const float pbk = pb[k];
    const float gbk = gb[k];
#pragma unroll
    for (int i = 0; i < 8; ++i) {
      Ps[k][p0 + i] = pa[i] + pbk;
      Gs[k][p0 + i] = ga[i] + gbk;
    }
  }
  __syncthreads();

  // M_c = P' G'^T  (each thread: 4 outputs), atomic-accumulate into Mg
  {
    const int kk = t & 31;
    const int l0 = (t >> 5) * 4;
    float m[4] = {};
    for (int p = 0; p < CH; ++p) {
      const float pv = Ps[kk][p];
#pragma unroll
      for (int j = 0; j < 4; ++j) m[j] += pv * Gs[l0 + j][p];
    }
    float* Mb = Mg + batch * CI * CI;
#pragma unroll
    for (int j = 0; j < 4; ++j)
      unsafeAtomicAdd(&Mb[kk * CI + l0 + j], m[j]);
  }
}

// ---------------------------------------------------------------------------
// k2: per-block redundant algebra (W = rw M^T tw / N, b = rw M^T tb / N + rb)
//     then apply Z = X + W X + b on this block's 64-px tile.
// ---------------------------------------------------------------------------
__global__ __launch_bounds__(256) void k2_apply(
    const float* __restrict__ x, const float* __restrict__ tw,
    const float* __restrict__ tb, const float* __restrict__ rw,
    const float* __restrict__ rb, const float* __restrict__ Mg,
    float* __restrict__ z) {
  __shared__ float Ms[CI][CI + 2];   // 4.3 KB
  __shared__ float T1[CI][CC + 2];   // 8.4 KB  (M^T tw)
  __shared__ float Wt[CC][CC + 4];   // 17.4 KB  Wt[in_j][out_o]
  __shared__ float xt[CC][CH + 4];   // 17.4 KB
  __shared__ float t2[CI];
  __shared__ float bl[CC];
  const int t = threadIdx.x;
  const int blk = blockIdx.x;
  const int batch = blk / NCHK;
  const int chk = blk - batch * NCHK;

  // load M (kernel edge provides coherence for k1's atomic writes)
  const float* __restrict__ Mb = Mg + batch * CI * CI;
  for (int idx = t; idx < CI * CI; idx += 256)
    Ms[idx >> 5][idx & 31] = Mb[idx];
  // stage x tile concurrently (independent of M)
#pragma unroll
  for (int h = 0; h < 4; ++h) {
    const int idx = t + 256 * h;
    const int c = idx >> 4;
    const int p4 = (idx & 15) * 4;
    const float4 v = *reinterpret_cast<const float4*>(
        &x[(size_t)batch * CC * NPIX + (size_t)c * NPIX + chk * CH + p4]);
    *reinterpret_cast<float4*>(&xt[c][p4]) = v;
  }
  __syncthreads();

  // T1[c][j] = sum_k M[k][c] tw[k][j];  t2[c] = sum_k M[k][c] tb[k]
  {
    const int j = t & 63;
    const int c0 = (t >> 6) * 8;
#pragma unroll
    for (int cc = 0; cc < 8; ++cc) {
      const int c = c0 + cc;
      float s = 0.f;
      for (int k = 0; k < CI; ++k) s += Ms[k][c] * tw[k * CC + j];
      T1[c][j] = s;
    }
    if (t < CI) {
      float s = 0.f;
      for (int k = 0; k < CI; ++k) s += Ms[k][t] * tb[k];
      t2[t] = s;
    }
  }
  __syncthreads();

  // Wt[j][o] = invN * sum_c rw[o][c] T1[c][j];  bl[o] = invN*rw.t2 + rb
  {
    const float invN = 1.0f / (float)NPIX;
    const int j = t & 63;
    const int o0 = (t >> 6) * 16;
#pragma unroll
    for (int oo = 0; oo < 16; ++oo) {
      const int o = o0 + oo;
      float s = 0.f;
      for (int c = 0; c < CI; ++c) s += rw[o * CI + c] * T1[c][j];
      Wt[j][o] = s * invN;
    }
    if (t < CC) {
      float s = 0.f;
      for (int c = 0; c < CI; ++c) s += rw[t * CI + c] * t2[c];
      bl[t] = s * invN + rb[t];
    }
  }
  __syncthreads();

  // apply: Z = X + W X + b  (each thread: 8 out-channels x 2 pixels)
  {
    const int n0 = chk * CH;
    float* __restrict__ Z = z + (size_t)batch * CC * NPIX;
    const int c0 = (t >> 5) * 8;
    const int m0 = (t & 31) * 2;
    float acc[8][2] = {};
#pragma unroll 8
    for (int k = 0; k < CC; ++k) {
      const float2 xv = *reinterpret_cast<const float2*>(&xt[k][m0]);
      const float4 w0 = *reinterpret_cast<const float4*>(&Wt[k][c0]);
      const float4 w1 = *reinterpret_cast<const float4*>(&Wt[k][c0 + 4]);
      const float wa[8] = {w0.x, w0.y, w0.z, w0.w, w1.x, w1.y, w1.z, w1.w};
#pragma unroll
      for (int cc = 0; cc < 8; ++cc) {
        acc[cc][0] += wa[cc] * xv.x;
        acc[cc][1] += wa[cc] * xv.y;
      }
    }
#pragma unroll
    for (int cc = 0; cc < 8; ++cc) {
      const int c = c0 + cc;
      const float2 xr = *reinterpret_cast<const float2*>(&xt[c][m0]);
      const float bb2 = bl[c];
      float2 o;
      o.x = acc[cc][0] + xr.x + bb2;
      o.y = acc[cc][1] + xr.y + bb2;
      *reinterpret_cast<float2*>(&Z[(size_t)c * NPIX + n0 + m0]) = o;
    }
  }
}

extern "C" void kernel_launch(void* const* d_in, const int* in_sizes, int n_in,
                              void* d_out, int out_size, void* d_ws,
                              size_t ws_size, hipStream_t stream) {
  (void)in_sizes; (void)n_in; (void)out_size; (void)ws_size;
  const float* x  = (const float*)d_in[0];
  const float* tw = (const float*)d_in[1];
  const float* tb = (const float*)d_in[2];
  const float* pw = (const float*)d_in[3];
  const float* pb = (const float*)d_in[4];
  const float* gw = (const float*)d_in[5];
  const float* gb = (const float*)d_in[6];
  const float* rw = (const float*)d_in[7];
  const float* rb = (const float*)d_in[8];
  float* z = (float*)d_out;

  float* Mg = (float*)d_ws;  // BB * 32 * 32 floats

  hipMemsetAsync(Mg, 0, (size_t)BB * CI * CI * sizeof(float), stream);
  hipLaunchKernelGGL(k1_M, dim3(NB), dim3(256), 0, stream,
                     x, pw, pb, gw, gb, Mg);
  hipLaunchKernelGGL(k2_apply, dim3(NB), dim3(256), 0, stream,
                     x, tw, tb, rw, rb, Mg, z);
}

// Round 8
// 34.944 us; speedup vs baseline: 2.0811x; 2.0811x over previous
//
#include <hip/hip_runtime.h>

#define BB 2
#define CC 64
#define CI 32
#define NPIX 9216          // 96*96
#define CH 128             // pixels per chunk
#define NCHK (NPIX / CH)   // 72 chunks per batch
#define NB (BB * NCHK)     // 144 blocks

// ---------------------------------------------------------------------------
// k1: per-(batch,chunk) partial M_c = (pw Xc + pb 1^T)(gw Xc + gb 1^T)^T
//     written to a DISTINCT 1024-float slot (plain stores, no atomics).
// ---------------------------------------------------------------------------
__global__ __launch_bounds__(256) void k1_Mpart(
    const float* __restrict__ x, const float* __restrict__ pw,
    const float* __restrict__ pb, const float* __restrict__ gw,
    const float* __restrict__ gb, float* __restrict__ Mpart) {
  __shared__ float xt[CC][CH + 4];   // 33.8 KB
  __shared__ float pws[CI][CC + 1];  // 8.3 KB
  __shared__ float gws[CI][CC + 1];  // 8.3 KB
  __shared__ float Ps[CI][CH + 4];   // 16.9 KB
  __shared__ float Gs[CI][CH + 4];   // 16.9 KB
  const int t = threadIdx.x;
  const int blk = blockIdx.x;
  const int batch = blk / NCHK;
  const int chk = blk - batch * NCHK;
  const float* __restrict__ X = x + (size_t)batch * CC * NPIX + chk * CH;

  // stage X chunk (64ch x 128px) coalesced float4: 2048 float4s, 8/thread
#pragma unroll
  for (int h = 0; h < 8; ++h) {
    const int idx = t + 256 * h;
    const int c = idx >> 5;
    const int p4 = (idx & 31) * 4;
    *reinterpret_cast<float4*>(&xt[c][p4]) =
        *reinterpret_cast<const float4*>(&X[(size_t)c * NPIX + p4]);
  }
  for (int idx = t; idx < CI * CC; idx += 256) {
    const int k = idx >> 6, c = idx & 63;
    pws[k][c] = pw[idx];
    gws[k][c] = gw[idx];
  }
  __syncthreads();

  // P' = pw Xc + pb, G' = gw Xc + gb: thread = (k, 16-px strip)
  {
    const int k = t & 31;
    const int p0 = (t >> 5) * 16;
    float pa[16] = {};
    float ga[16] = {};
    for (int c = 0; c < CC; ++c) {
      const float pwv = pws[k][c];
      const float gwv = gws[k][c];
#pragma unroll
      for (int i = 0; i < 16; ++i) {
        const float xv = xt[c][p0 + i];
        pa[i] += pwv * xv;
        ga[i] += gwv * xv;
      }
    }
    const float pbk = pb[k];
    const float gbk = gb[k];
#pragma unroll
    for (int i = 0; i < 16; ++i) {
      Ps[k][p0 + i] = pa[i] + pbk;
      Gs[k][p0 + i] = ga[i] + gbk;
    }
  }
  __syncthreads();

  // M_c = P' G'^T: thread = (row kk, 4 cols), float4 over 128 pixels
  {
    const int kk = t & 31;
    const int l0 = (t >> 5) * 4;
    float m[4] = {};
    for (int p4 = 0; p4 < CH; p4 += 4) {
      const float4 pv = *reinterpret_cast<const float4*>(&Ps[kk][p4]);
#pragma unroll
      for (int j = 0; j < 4; ++j) {
        const float4 gv = *reinterpret_cast<const float4*>(&Gs[l0 + j][p4]);
        m[j] += pv.x * gv.x + pv.y * gv.y + pv.z * gv.z + pv.w * gv.w;
      }
    }
    float* Mp = Mpart + ((size_t)batch * NCHK + chk) * (CI * CI);
    *reinterpret_cast<float4*>(&Mp[kk * CI + l0]) =
        make_float4(m[0], m[1], m[2], m[3]);
  }
}

// ---------------------------------------------------------------------------
// k2: redundant per-block: reduce 72 M-partials -> M, algebra
//     (W = rw M^T tw / N, b = rw M^T tb / N + rb), apply Z = X + W X + b.
// ---------------------------------------------------------------------------
__global__ __launch_bounds__(256) void k2_apply(
    const float* __restrict__ x, const float* __restrict__ tw,
    const float* __restrict__ tb, const float* __restrict__ rw,
    const float* __restrict__ rb, const float* __restrict__ Mpart,
    float* __restrict__ z) {
  __shared__ float Ms[CI][CI + 2];   // 4.3 KB
  __shared__ float T1[CI][CC + 2];   // 8.4 KB
  __shared__ float Wt[CC][CC + 4];   // 17.4 KB  Wt[in_j][out_o]
  __shared__ float xt[CC][CH + 4];   // 33.8 KB
  __shared__ float t2[CI];
  __shared__ float bl[CC];
  const int t = threadIdx.x;
  const int blk = blockIdx.x;
  const int batch = blk / NCHK;
  const int chk = blk - batch * NCHK;

  // stage x tile first (independent of M; hides Mpart latency)
#pragma unroll
  for (int h = 0; h < 8; ++h) {
    const int idx = t + 256 * h;
    const int c = idx >> 5;
    const int p4 = (idx & 31) * 4;
    *reinterpret_cast<float4*>(&xt[c][p4]) = *reinterpret_cast<const float4*>(
        &x[(size_t)batch * CC * NPIX + (size_t)c * NPIX + chk * CH + p4]);
  }

  // reduce M partials: thread t owns elements {t, t+256, t+512, t+768}
  {
    const float* __restrict__ Mp =
        Mpart + (size_t)batch * NCHK * (CI * CI);
    float s0 = 0.f, s1 = 0.f, s2 = 0.f, s3 = 0.f;
#pragma unroll 4
    for (int k = 0; k < NCHK; ++k) {
      const float* row = Mp + (size_t)k * (CI * CI);
      s0 += row[t];
      s1 += row[t + 256];
      s2 += row[t + 512];
      s3 += row[t + 768];
    }
    Ms[(t) >> 5][(t) & 31] = s0;
    Ms[(t + 256) >> 5][(t + 256) & 31] = s1;
    Ms[(t + 512) >> 5][(t + 512) & 31] = s2;
    Ms[(t + 768) >> 5][(t + 768) & 31] = s3;
  }
  __syncthreads();

  // T1[c][j] = sum_k M[k][c] tw[k][j];  t2[c] = sum_k M[k][c] tb[k]
  {
    const int j = t & 63;
    const int c0 = (t >> 6) * 8;
#pragma unroll
    for (int cc = 0; cc < 8; ++cc) {
      const int c = c0 + cc;
      float s = 0.f;
      for (int k = 0; k < CI; ++k) s += Ms[k][c] * tw[k * CC + j];
      T1[c][j] = s;
    }
    if (t < CI) {
      float s = 0.f;
      for (int k = 0; k < CI; ++k) s += Ms[k][t] * tb[k];
      t2[t] = s;
    }
  }
  __syncthreads();

  // Wt[j][o] = invN * sum_c rw[o][c] T1[c][j];  bl[o] = invN*rw.t2 + rb
  {
    const float invN = 1.0f / (float)NPIX;
    const int j = t & 63;
    const int o0 = (t >> 6) * 16;
#pragma unroll
    for (int oo = 0; oo < 16; ++oo) {
      const int o = o0 + oo;
      float s = 0.f;
      for (int c = 0; c < CI; ++c) s += rw[o * CI + c] * T1[c][j];
      Wt[j][o] = s * invN;
    }
    if (t < CC) {
      float s = 0.f;
      for (int c = 0; c < CI; ++c) s += rw[t * CI + c] * t2[c];
      bl[t] = s * invN + rb[t];
    }
  }
  __syncthreads();

  // apply: Z = X + W X + b  (thread: 8 out-channels x 4 pixels)
  {
    const int n0 = chk * CH;
    float* __restrict__ Z = z + (size_t)batch * CC * NPIX;
    const int c0 = (t >> 5) * 8;
    const int m0 = (t & 31) * 4;
    float acc[8][4] = {};
#pragma unroll 8
    for (int k = 0; k < CC; ++k) {
      const float4 xv = *reinterpret_cast<const float4*>(&xt[k][m0]);
      const float4 w0 = *reinterpret_cast<const float4*>(&Wt[k][c0]);
      const float4 w1 = *reinterpret_cast<const float4*>(&Wt[k][c0 + 4]);
      const float xa[4] = {xv.x, xv.y, xv.z, xv.w};
      const float wa[8] = {w0.x, w0.y, w0.z, w0.w, w1.x, w1.y, w1.z, w1.w};
#pragma unroll
      for (int cc = 0; cc < 8; ++cc)
#pragma unroll
        for (int nn = 0; nn < 4; ++nn) acc[cc][nn] += wa[cc] * xa[nn];
    }
#pragma unroll
    for (int cc = 0; cc < 8; ++cc) {
      const int c = c0 + cc;
      const float4 xr = *reinterpret_cast<const float4*>(&xt[c][m0]);
      const float bb2 = bl[c];
      float4 o;
      o.x = acc[cc][0] + xr.x + bb2;
      o.y = acc[cc][1] + xr.y + bb2;
      o.z = acc[cc][2] + xr.z + bb2;
      o.w = acc[cc][3] + xr.w + bb2;
      *reinterpret_cast<float4*>(&Z[(size_t)c * NPIX + n0 + m0]) = o;
    }
  }
}

extern "C" void kernel_launch(void* const* d_in, const int* in_sizes, int n_in,
                              void* d_out, int out_size, void* d_ws,
                              size_t ws_size, hipStream_t stream) {
  (void)in_sizes; (void)n_in; (void)out_size; (void)ws_size;
  const float* x  = (const float*)d_in[0];
  const float* tw = (const float*)d_in[1];
  const float* tb = (const float*)d_in[2];
  const float* pw = (const float*)d_in[3];
  const float* pb = (const float*)d_in[4];
  const float* gw = (const float*)d_in[5];
  const float* gb = (const float*)d_in[6];
  const float* rw = (const float*)d_in[7];
  const float* rb = (const float*)d_in[8];
  float* z = (float*)d_out;

  float* Mpart = (float*)d_ws;  // BB * NCHK * 1024 floats = 589 KB

  hipLaunchKernelGGL(k1_Mpart, dim3(NB), dim3(256), 0, stream,
                     x, pw, pb, gw, gb, Mpart);
  hipLaunchKernelGGL(k2_apply, dim3(NB), dim3(256), 0, stream,
                     x, tw, tb, rw, rb, Mpart, z);
}

// Round 9
// 29.223 us; speedup vs baseline: 2.4885x; 1.1958x over previous
//
#include <hip/hip_runtime.h>

#define BB 2
#define CC 64
#define CI 32
#define NPIX 9216          // 96*96
#define CH 128             // pixels per chunk
#define NCHK (NPIX / CH)   // 72 chunks per batch
#define NB (BB * NCHK)     // 144 blocks

// ---------------------------------------------------------------------------
// k1: per-(batch,chunk) partial M_c = (pw Xc + pb 1^T)(gw Xc + gb 1^T)^T
//     -> distinct 1024-float slot. 512 threads (2 waves/SIMD).
// ---------------------------------------------------------------------------
__global__ __launch_bounds__(512) void k1_Mpart(
    const float* __restrict__ x, const float* __restrict__ pw,
    const float* __restrict__ pb, const float* __restrict__ gw,
    const float* __restrict__ gb, float* __restrict__ Mpart) {
  __shared__ float xt[CC][CH + 4];      // 33.8 KB
  __shared__ float pgw[2 * CI][CC + 1]; // 16.6 KB (pw rows 0..31, gw rows 32..63)
  __shared__ float Ps[CI][CH + 4];      // 16.9 KB
  __shared__ float Gs[CI][CH + 4];      // 16.9 KB
  const int t = threadIdx.x;
  const int blk = blockIdx.x;
  const int batch = blk / NCHK;
  const int chk = blk - batch * NCHK;
  const float* __restrict__ X = x + (size_t)batch * CC * NPIX + chk * CH;

  // stage X chunk (64ch x 128px): 2048 float4, 4 per thread, coalesced
#pragma unroll
  for (int h = 0; h < 4; ++h) {
    const int idx = t + 512 * h;
    const int c = idx >> 5;
    const int p4 = (idx & 31) * 4;
    *reinterpret_cast<float4*>(&xt[c][p4]) =
        *reinterpret_cast<const float4*>(&X[(size_t)c * NPIX + p4]);
  }
  // stage pw+gw (2048 floats each row-major 32x64)
#pragma unroll
  for (int h = 0; h < 4; ++h) {
    const int idx = t + 512 * h;
    const int k = idx >> 6, c = idx & 63;
    pgw[k][c] = pw[idx];
    pgw[CI + k][c] = gw[idx];
  }
  __syncthreads();

  // P' = pw Xc + pb, G' = gw Xc + gb : thread = (k = t&31, 8-px strip)
  {
    const int k = t & 31;
    const int p0 = (t >> 5) * 8;
    float pa[8] = {};
    float ga[8] = {};
    for (int c = 0; c < CC; ++c) {
      const float4 x0 = *reinterpret_cast<const float4*>(&xt[c][p0]);
      const float4 x1 = *reinterpret_cast<const float4*>(&xt[c][p0 + 4]);
      const float pv = pgw[k][c];
      const float gv = pgw[CI + k][c];
      const float xa[8] = {x0.x, x0.y, x0.z, x0.w, x1.x, x1.y, x1.z, x1.w};
#pragma unroll
      for (int i = 0; i < 8; ++i) {
        pa[i] += pv * xa[i];
        ga[i] += gv * xa[i];
      }
    }
    const float pbk = pb[k];
    const float gbk = gb[k];
    float4 o0, o1;
    o0 = make_float4(pa[0] + pbk, pa[1] + pbk, pa[2] + pbk, pa[3] + pbk);
    o1 = make_float4(pa[4] + pbk, pa[5] + pbk, pa[6] + pbk, pa[7] + pbk);
    *reinterpret_cast<float4*>(&Ps[k][p0]) = o0;
    *reinterpret_cast<float4*>(&Ps[k][p0 + 4]) = o1;
    o0 = make_float4(ga[0] + gbk, ga[1] + gbk, ga[2] + gbk, ga[3] + gbk);
    o1 = make_float4(ga[4] + gbk, ga[5] + gbk, ga[6] + gbk, ga[7] + gbk);
    *reinterpret_cast<float4*>(&Gs[k][p0]) = o0;
    *reinterpret_cast<float4*>(&Gs[k][p0 + 4]) = o1;
  }
  __syncthreads();

  // M_c = P' G'^T : thread = (kk = t>>4, l = t&15), outputs (kk,l),(kk,l+16)
  {
    const int kk = t >> 4;
    const int l = t & 15;
    float ma = 0.f, mb = 0.f;
    for (int p4 = 0; p4 < CH; p4 += 4) {
      const float4 pv = *reinterpret_cast<const float4*>(&Ps[kk][p4]);
      const float4 g0 = *reinterpret_cast<const float4*>(&Gs[l][p4]);
      const float4 g1 = *reinterpret_cast<const float4*>(&Gs[l + 16][p4]);
      ma += pv.x * g0.x + pv.y * g0.y + pv.z * g0.z + pv.w * g0.w;
      mb += pv.x * g1.x + pv.y * g1.y + pv.z * g1.z + pv.w * g1.w;
    }
    float* Mp = Mpart + ((size_t)batch * NCHK + chk) * (CI * CI);
    Mp[kk * CI + l] = ma;
    Mp[kk * CI + l + 16] = mb;
  }
}

// ---------------------------------------------------------------------------
// k2: redundant per-block: reduce 72 M-partials -> M, algebra
//     (W = rw M^T tw / N, b = rw M^T tb / N + rb), apply Z = X + W X + b.
//     512 threads (2 waves/SIMD).
// ---------------------------------------------------------------------------
__global__ __launch_bounds__(512) void k2_apply(
    const float* __restrict__ x, const float* __restrict__ tw,
    const float* __restrict__ tb, const float* __restrict__ rw,
    const float* __restrict__ rb, const float* __restrict__ Mpart,
    float* __restrict__ z) {
  __shared__ float xt[CC][CH + 4];   // 33.8 KB
  __shared__ float Ms[CI][CI + 1];   // 4.2 KB
  __shared__ float T1[CI][CC + 2];   // 8.4 KB
  __shared__ float Wt[CC][CC + 2];   // 16.9 KB (first 8 KB doubles as red[])
  __shared__ float t2[CI];
  __shared__ float bl[CC];
  const int t = threadIdx.x;
  const int blk = blockIdx.x;
  const int batch = blk / NCHK;
  const int chk = blk - batch * NCHK;

  // stage x tile (2048 float4, 4/thread)
#pragma unroll
  for (int h = 0; h < 4; ++h) {
    const int idx = t + 512 * h;
    const int c = idx >> 5;
    const int p4 = (idx & 31) * 4;
    *reinterpret_cast<float4*>(&xt[c][p4]) = *reinterpret_cast<const float4*>(
        &x[(size_t)batch * CC * NPIX + (size_t)c * NPIX + chk * CH + p4]);
  }

  // M-reduce: halves of the 72 slots across thread-halves, float4 rows
  float4* red = reinterpret_cast<float4*>(&Wt[0][0]);  // red[512]
  {
    const int e = t & 255;   // float4 element 0..255
    const int half = t >> 8; // 0/1
    const float* __restrict__ Mp =
        Mpart + (size_t)batch * NCHK * (CI * CI) + (size_t)e * 4;
    float4 s = make_float4(0.f, 0.f, 0.f, 0.f);
#pragma unroll 4
    for (int k = half * 36; k < half * 36 + 36; ++k) {
      const float4 v =
          *reinterpret_cast<const float4*>(&Mp[(size_t)k * (CI * CI)]);
      s.x += v.x; s.y += v.y; s.z += v.z; s.w += v.w;
    }
    red[half * 256 + e] = s;
  }
  __syncthreads();
  if (t < 256) {
    const float4 a = red[t];
    const float4 b = red[t + 256];
    const int m0 = t * 4;
    Ms[(m0 + 0) >> 5][(m0 + 0) & 31] = a.x + b.x;
    Ms[(m0 + 1) >> 5][(m0 + 1) & 31] = a.y + b.y;
    Ms[(m0 + 2) >> 5][(m0 + 2) & 31] = a.z + b.z;
    Ms[(m0 + 3) >> 5][(m0 + 3) & 31] = a.w + b.w;
  }
  __syncthreads();

  // T1[c][j] = sum_k Ms[k][c] tw[k][j];  t2[c] = sum_k Ms[k][c] tb[k]
  {
    const int j = t & 63;
    const int c0 = (t >> 6) * 4;  // 4 c per thread
#pragma unroll
    for (int cc = 0; cc < 4; ++cc) {
      const int c = c0 + cc;
      float s = 0.f;
      for (int k = 0; k < CI; ++k) s += Ms[k][c] * tw[k * CC + j];
      T1[c][j] = s;
    }
    if (t < CI) {
      float s = 0.f;
      for (int k = 0; k < CI; ++k) s += Ms[k][t] * tb[k];
      t2[t] = s;
    }
  }
  __syncthreads();

  // Wt[j][o] = invN * sum_c rw[o][c] T1[c][j]  (overwrites red region - dead)
  {
    const float invN = 1.0f / (float)NPIX;
    const int j = t & 63;
    const int o0 = (t >> 6) * 8;  // 8 o per thread
#pragma unroll
    for (int oo = 0; oo < 8; ++oo) {
      const int o = o0 + oo;
      float s = 0.f;
      for (int c = 0; c < CI; ++c) s += rw[o * CI + c] * T1[c][j];
      Wt[j][o] = s * invN;
    }
    if (t < CC) {
      float s = 0.f;
      for (int c = 0; c < CI; ++c) s += rw[t * CI + c] * t2[c];
      bl[t] = s * invN + rb[t];
    }
  }
  __syncthreads();

  // apply: Z = X + W X + b : thread = (8 out-ch, 2 px)
  {
    const int n0 = chk * CH;
    float* __restrict__ Z = z + (size_t)batch * CC * NPIX;
    const int c0 = (t >> 6) * 8;
    const int m0 = (t & 63) * 2;
    float acc[8][2] = {};
#pragma unroll 8
    for (int k = 0; k < CC; ++k) {
      const float2 xv = *reinterpret_cast<const float2*>(&xt[k][m0]);
      const float4 w0 = *reinterpret_cast<const float4*>(&Wt[k][c0]);
      const float4 w1 = *reinterpret_cast<const float4*>(&Wt[k][c0 + 4]);
      const float wa[8] = {w0.x, w0.y, w0.z, w0.w, w1.x, w1.y, w1.z, w1.w};
#pragma unroll
      for (int cc = 0; cc < 8; ++cc) {
        acc[cc][0] += wa[cc] * xv.x;
        acc[cc][1] += wa[cc] * xv.y;
      }
    }
#pragma unroll
    for (int cc = 0; cc < 8; ++cc) {
      const int c = c0 + cc;
      const float2 xr = *reinterpret_cast<const float2*>(&xt[c][m0]);
      const float bb2 = bl[c];
      float2 o;
      o.x = acc[cc][0] + xr.x + bb2;
      o.y = acc[cc][1] + xr.y + bb2;
      *reinterpret_cast<float2*>(&Z[(size_t)c * NPIX + n0 + m0]) = o;
    }
  }
}

extern "C" void kernel_launch(void* const* d_in, const int* in_sizes, int n_in,
                              void* d_out, int out_size, void* d_ws,
                              size_t ws_size, hipStream_t stream) {
  (void)in_sizes; (void)n_in; (void)out_size; (void)ws_size;
  const float* x  = (const float*)d_in[0];
  const float* tw = (const float*)d_in[1];
  const float* tb = (const float*)d_in[2];
  const float* pw = (const float*)d_in[3];
  const float* pb = (const float*)d_in[4];
  const float* gw = (const float*)d_in[5];
  const float* gb = (const float*)d_in[6];
  const float* rw = (const float*)d_in[7];
  const float* rb = (const float*)d_in[8];
  float* z = (float*)d_out;

  float* Mpart = (float*)d_ws;  // NB * 1024 floats = 589 KB

  hipLaunchKernelGGL(k1_Mpart, dim3(NB), dim3(512), 0, stream,
                     x, pw, pb, gw, gb, Mpart);
  hipLaunchKernelGGL(k2_apply, dim3(NB), dim3(512), 0, stream,
                     x, tw, tb, rw, rb, Mpart, z);
}